// Round 2
// baseline (170.938 us; speedup 1.0000x reference)
//
#include <hip/hip_runtime.h>

// QueryEncDec: 2 stacks x 128 layers of scalar GRU (H=in=1), T=256.
// Barrier-free wavefront: thread l = global layer l (0..127 enc, 128..255 dec).
// Intra-wave layer handoff via DPP wave_shr:1 (register shift, no sync).
// Cross-wave handoff (3 boundaries) via LDS mailbox: 8-byte {tag,val} relaxed
// atomics -- tag and data travel in one ds_*_b64, so no fence is needed.
// Each wave free-runs its own 319-step local diagonal loop; consumer waves
// self-throttle on the mailbox tags (spin only during pipeline fill).

#define T_LEN   256
#define NLAYERS 256
#define DPP_WAVE_SHR1 0x138

__device__ __forceinline__ float fexp(float x) {
    return __builtin_amdgcn_exp2f(x * 1.44269504088896340736f);
}
__device__ __forceinline__ float frcp(float x) {
    return __builtin_amdgcn_rcpf(x);
}
__device__ __forceinline__ float fsigmoid(float x) {
    return frcp(1.0f + fexp(-x));
}
__device__ __forceinline__ float ftanh(float x) {
    return 1.0f - 2.0f * frcp(fexp(2.0f * x) + 1.0f);
}

__global__ __launch_bounds__(256, 1) void gru_pipe(
    const float* __restrict__ X,
    const float* __restrict__ enc_w_ih, const float* __restrict__ enc_w_hh,
    const float* __restrict__ enc_b_ih, const float* __restrict__ enc_b_hh,
    const float* __restrict__ dec_w_ih, const float* __restrict__ dec_w_hh,
    const float* __restrict__ dec_b_ih, const float* __restrict__ dec_b_hh,
    float* __restrict__ out)
{
    const int tid  = threadIdx.x;       // global layer index 0..255
    const int w    = tid >> 6;          // wave 0..3 (64 layers each)
    const int lane = tid & 63;

    __shared__ float xs[T_LEN];
    __shared__ unsigned long long bnd[3][T_LEN];  // {tag=t+1 (hi32), val (lo32)}

    xs[tid] = X[tid];
    bnd[0][tid] = 0ull;
    bnd[1][tid] = 0ull;
    bnd[2][tid] = 0ull;

    // per-layer scalar params (torch gate order r,z,n)
    const int pl = tid & 127;
    const float* wip = (tid < 128) ? enc_w_ih : dec_w_ih;
    const float* whp = (tid < 128) ? enc_w_hh : dec_w_hh;
    const float* bip = (tid < 128) ? enc_b_ih : dec_b_ih;
    const float* bhp = (tid < 128) ? enc_b_hh : dec_b_hh;
    const float wi0 = wip[pl * 3 + 0], wi1 = wip[pl * 3 + 1], wi2 = wip[pl * 3 + 2];
    const float wh0 = whp[pl * 3 + 0], wh1 = whp[pl * 3 + 1], wh2 = whp[pl * 3 + 2];
    const float bi0 = bip[pl * 3 + 0], bi1 = bip[pl * 3 + 1], bi2 = bip[pl * 3 + 2];
    const float bh0 = bhp[pl * 3 + 0], bh1 = bhp[pl * 3 + 1], bh2 = bhp[pl * 3 + 2];

    __syncthreads();                    // the ONLY block barrier

    float h = 0.0f;
    // lane-0 input prefetch state (all lanes compute it -> uniform, broadcast LDS reads)
    float xcur = 0.0f;                  // wave 0: xs[s]
    unsigned long long pfA = 0ull, pfB = 0ull;  // wave>0: slots s, s+1
    if (w == 0) {
        xcur = xs[0];
    } else {
        pfA = __atomic_load_n(&bnd[w - 1][0], __ATOMIC_RELAXED);
        pfB = __atomic_load_n(&bnd[w - 1][1], __ATOMIC_RELAXED);
    }

    const int S = 64 + T_LEN - 1;       // 319 local diagonal steps per wave
    for (int s = 0; s < S; ++s) {
        // 1) intra-wave handoff: lane i gets lane i-1's h from previous step
        const int hb = __builtin_bit_cast(int, h);
        const int xb = __builtin_amdgcn_update_dpp(0, hb, DPP_WAVE_SHR1, 0xF, 0xF, false);
        float x = __builtin_bit_cast(float, xb);

        // 2) lane-0 input (uniform per wave; only lane 0 consumes)
        float x0 = 0.0f;
        if (w == 0) {
            x0 = xcur;
            xcur = xs[(s + 1 < T_LEN) ? s + 1 : T_LEN - 1];
        } else {
            if (s < T_LEN) {
                unsigned long long v = pfA;
                while ((unsigned)(v >> 32) != (unsigned)(s + 1)) {
                    v = __atomic_load_n(&bnd[w - 1][s], __ATOMIC_RELAXED);
                }
                x0 = __builtin_bit_cast(float, (unsigned)v);
            }
            pfA = pfB;
            if (s + 2 < T_LEN) {
                pfB = __atomic_load_n(&bnd[w - 1][s + 2], __ATOMIC_RELAXED);
            }
        }
        if (lane == 0) x = x0;

        // 3) GRU cell (computed by all lanes, committed only when active)
        const int t = s - lane;
        const bool act = (unsigned)t < (unsigned)T_LEN;

        const float gh0 = __builtin_fmaf(wh0, h, bh0);
        const float gh1 = __builtin_fmaf(wh1, h, bh1);
        const float gh2 = __builtin_fmaf(wh2, h, bh2);
        const float gi0 = __builtin_fmaf(wi0, x, bi0);
        const float gi1 = __builtin_fmaf(wi1, x, bi1);
        const float gi2 = __builtin_fmaf(wi2, x, bi2);

        const float r = fsigmoid(gi0 + gh0);
        const float z = fsigmoid(gi1 + gh1);
        const float n = ftanh(__builtin_fmaf(r, gh2, gi2));
        const float hc = n + z * (h - n);
        h = act ? hc : h;

        // 4) boundary publish / final output
        if (lane == 63 && act) {
            if (w < 3) {
                const unsigned long long pk =
                    ((unsigned long long)(unsigned)(t + 1) << 32) |
                    (unsigned long long)__builtin_bit_cast(unsigned, h);
                __atomic_store_n(&bnd[w][t], pk, __ATOMIC_RELAXED);
            } else {
                out[t] = h;             // dec_out[t] (layer 255)
            }
        }
    }

    // dec_h: final hidden of decoder layers (threads 128..255)
    if (tid >= 128) out[T_LEN + (tid - 128)] = h;
}

extern "C" void kernel_launch(void* const* d_in, const int* in_sizes, int n_in,
                              void* d_out, int out_size, void* d_ws, size_t ws_size,
                              hipStream_t stream) {
    const float* X        = (const float*)d_in[0];
    const float* enc_w_ih = (const float*)d_in[1];
    const float* enc_w_hh = (const float*)d_in[2];
    const float* enc_b_ih = (const float*)d_in[3];
    const float* enc_b_hh = (const float*)d_in[4];
    const float* dec_w_ih = (const float*)d_in[5];
    const float* dec_w_hh = (const float*)d_in[6];
    const float* dec_b_ih = (const float*)d_in[7];
    const float* dec_b_hh = (const float*)d_in[8];
    float* out = (float*)d_out;

    gru_pipe<<<1, 256, 0, stream>>>(X,
                                    enc_w_ih, enc_w_hh, enc_b_ih, enc_b_hh,
                                    dec_w_ih, dec_w_hh, dec_b_ih, dec_b_hh,
                                    out);
}

// Round 3
// 143.614 us; speedup vs baseline: 1.1903x; 1.1903x over previous
//
#include <hip/hip_runtime.h>

// QueryEncDec: 2 stacks x 128 layers of scalar GRU (H=in=1), T=256.
// Wavefront: thread l = global layer l (0..127 enc, 128..255 dec), 4 waves.
// Intra-wave layer handoff: DPP wave_shr:1 (register shift, no sync).
// Cross-wave handoff: LDS mailbox {tag,val} packed in one u64 (single-copy
// atomic ds_*_b64, no fence). Consumer pre-spins until producer is 8 slots
// ahead, then a 3-deep prefetch ring always hits (no steady-state spinning).
// All per-iteration branches removed: clamped addresses + cndmask + dump slots.
// Gate math has log2e/2.0 folded into the weights; epilogue is 1 fma after
// the last rcp: h' = fma(Q, 2z-2, fma(z, h-1, 1)).

#define T_LEN 256
typedef unsigned long long u64;

__device__ __forceinline__ float fexp2(float x) { return __builtin_amdgcn_exp2f(x); }
__device__ __forceinline__ float frcp(float x)  { return __builtin_amdgcn_rcpf(x); }

struct Cell {
    float wri, wrh, brc;   // r gate, pre-scaled by -log2(e)
    float wzi, wzh, bzc;   // z gate, pre-scaled by -log2(e)
    float wni, bni;        // n gate input half, pre-scaled by 2*log2(e)
    float wnh, bnh;        // n gate hidden half, pre-scaled by 2*log2(e)

    __device__ __forceinline__ float step(float x, float h) const {
        // E_r = e^{-(gi_r+gh_r)}, E_z likewise (constants folded into weights)
        const float er = fexp2(__builtin_fmaf(wri, x, __builtin_fmaf(wrh, h, brc)));
        const float ez = fexp2(__builtin_fmaf(wzi, x, __builtin_fmaf(wzh, h, bzc)));
        const float r  = frcp(1.0f + er);
        const float z  = frcp(1.0f + ez);
        const float ghn = __builtin_fmaf(wnh, h, bnh);   // 2log2e*(wh_n*h+bh_n)
        const float gin = __builtin_fmaf(wni, x, bni);   // 2log2e*(wi_n*x+bi_n)
        const float en  = fexp2(__builtin_fmaf(r, ghn, gin));  // e^{2v}
        const float q   = frcp(1.0f + en);               // n = 1-2q
        const float A   = __builtin_fmaf(z, h - 1.0f, 1.0f);   // off critical path
        const float B   = __builtin_fmaf(2.0f, z, -2.0f);      // 2z-2
        return __builtin_fmaf(q, B, A);                  // (1-z)n + z h
    }
};

template<bool FIRST, bool LAST>
__device__ __forceinline__ float run_wave(
    int lane, const Cell& c, const float* xs,
    u64* inbox, u64* outbox, u64* dumpL,
    float* out, float* dumpG)
{
    float h = 0.0f;
    float xA = 0.0f, xB = 0.0f;
    u64 pf0 = 0, pf1 = 0, pf2 = 0;

    if (FIRST) {
        xA = xs[0];
        xB = xs[1];
    } else {
        // establish >=8-slot lag so the 3-deep prefetch ring always hits
        while ((unsigned)(__atomic_load_n(&inbox[7], __ATOMIC_RELAXED) >> 32) != 8u) {}
        pf0 = __atomic_load_n(&inbox[0], __ATOMIC_RELAXED);
        pf1 = __atomic_load_n(&inbox[1], __ATOMIC_RELAXED);
        pf2 = __atomic_load_n(&inbox[2], __ATOMIC_RELAXED);
    }

    const int S = 64 + T_LEN - 1;   // 319 local diagonal steps
    for (int s = 0; s < S; ++s) {
        // neighbor handoff: lane i <- lane i-1's h (prev step); lane 0 <- feed
        const int hb = __builtin_bit_cast(int, h);
        const int xb = __builtin_amdgcn_update_dpp(0, hb, 0x138, 0xF, 0xF, false);
        float x = __builtin_bit_cast(float, xb);

        float x0;
        if (FIRST) {
            x0 = xA; xA = xB;
            int nx = s + 2; nx = (nx < T_LEN - 1) ? nx : (T_LEN - 1);
            xB = xs[nx];
        } else {
            const int c0 = (s < T_LEN - 1) ? s : (T_LEN - 1);
            const unsigned expt = (unsigned)c0 + 1u;
            u64 v = pf0;
            if ((unsigned)(v >> 32) != expt) {          // rarely taken after fill
                do { v = __atomic_load_n(&inbox[c0], __ATOMIC_RELAXED); }
                while ((unsigned)(v >> 32) != expt);
            }
            x0 = __builtin_bit_cast(float, (unsigned)v);
            pf0 = pf1; pf1 = pf2;
            int n3 = s + 3; n3 = (n3 < T_LEN - 1) ? n3 : (T_LEN - 1);
            pf2 = __atomic_load_n(&inbox[n3], __ATOMIC_RELAXED);
        }
        x = (lane == 0) ? x0 : x;

        const int t = s - lane;
        const bool act = (unsigned)t < (unsigned)T_LEN;
        const float hn = c.step(x, h);
        h = act ? hn : h;

        const int tw = s - 63;                          // lane 63's timestep
        if (!LAST) {
            // unconditional publish: out-of-range tags (tw+1 <= 0) never match
            const int slot = (tw > 0) ? tw : 0;
            const u64 pk = ((u64)(unsigned)(tw + 1) << 32) |
                           (u64)__builtin_bit_cast(unsigned, h);
            u64* p = (lane == 63) ? (outbox + slot) : (dumpL + lane);
            __atomic_store_n(p, pk, __ATOMIC_RELAXED);
        } else {
            const bool a3 = (unsigned)tw < (unsigned)T_LEN;
            float* p = (lane == 63 && a3) ? (out + tw) : (dumpG + lane);
            *p = h;                                     // dec_out[tw]
        }
    }
    return h;
}

__global__ __launch_bounds__(256, 1) void gru_pipe(
    const float* __restrict__ X,
    const float* __restrict__ enc_w_ih, const float* __restrict__ enc_w_hh,
    const float* __restrict__ enc_b_ih, const float* __restrict__ enc_b_hh,
    const float* __restrict__ dec_w_ih, const float* __restrict__ dec_w_hh,
    const float* __restrict__ dec_b_ih, const float* __restrict__ dec_b_hh,
    float* __restrict__ out, float* __restrict__ dumpG)
{
    const int tid  = threadIdx.x;       // global layer 0..255
    const int w    = tid >> 6;          // wave 0..3
    const int lane = tid & 63;

    __shared__ float xs[T_LEN];
    __shared__ u64 bnd[3][T_LEN];       // mailbox: hi32 = tag (t+1), lo32 = value
    __shared__ u64 dumpL[64];

    xs[tid] = X[tid];
    bnd[0][tid] = 0ull; bnd[1][tid] = 0ull; bnd[2][tid] = 0ull;

    // per-layer params (torch gate order r,z,n), constants folded
    const int pl = tid & 127;
    const float* wip = (tid < 128) ? enc_w_ih : dec_w_ih;
    const float* whp = (tid < 128) ? enc_w_hh : dec_w_hh;
    const float* bip = (tid < 128) ? enc_b_ih : dec_b_ih;
    const float* bhp = (tid < 128) ? enc_b_hh : dec_b_hh;
    const float L2E = 1.44269504088896340736f;
    Cell c;
    c.wri = -L2E * wip[pl * 3 + 0];
    c.wrh = -L2E * whp[pl * 3 + 0];
    c.brc = -L2E * (bip[pl * 3 + 0] + bhp[pl * 3 + 0]);
    c.wzi = -L2E * wip[pl * 3 + 1];
    c.wzh = -L2E * whp[pl * 3 + 1];
    c.bzc = -L2E * (bip[pl * 3 + 1] + bhp[pl * 3 + 1]);
    c.wni = 2.0f * L2E * wip[pl * 3 + 2];
    c.bni = 2.0f * L2E * bip[pl * 3 + 2];
    c.wnh = 2.0f * L2E * whp[pl * 3 + 2];
    c.bnh = 2.0f * L2E * bhp[pl * 3 + 2];

    __syncthreads();                    // the only block barrier

    float h;
    if      (w == 0) h = run_wave<true,  false>(lane, c, xs, nullptr, bnd[0], dumpL, nullptr, dumpG);
    else if (w == 1) h = run_wave<false, false>(lane, c, xs, bnd[0],  bnd[1], dumpL, nullptr, dumpG);
    else if (w == 2) h = run_wave<false, false>(lane, c, xs, bnd[1],  bnd[2], dumpL, nullptr, dumpG);
    else             h = run_wave<false, true >(lane, c, xs, bnd[2],  nullptr, dumpL, out,    dumpG);

    // dec_h: final hidden of decoder layers (global layers 128..255)
    if (tid >= 128) out[T_LEN + (tid - 128)] = h;
}

extern "C" void kernel_launch(void* const* d_in, const int* in_sizes, int n_in,
                              void* d_out, int out_size, void* d_ws, size_t ws_size,
                              hipStream_t stream) {
    const float* X        = (const float*)d_in[0];
    const float* enc_w_ih = (const float*)d_in[1];
    const float* enc_w_hh = (const float*)d_in[2];
    const float* enc_b_ih = (const float*)d_in[3];
    const float* enc_b_hh = (const float*)d_in[4];
    const float* dec_w_ih = (const float*)d_in[5];
    const float* dec_w_hh = (const float*)d_in[6];
    const float* dec_b_ih = (const float*)d_in[7];
    const float* dec_b_hh = (const float*)d_in[8];
    float* out = (float*)d_out;
    float* dumpG = (float*)d_ws;

    gru_pipe<<<1, 256, 0, stream>>>(X,
                                    enc_w_ih, enc_w_hh, enc_b_ih, enc_b_hh,
                                    dec_w_ih, dec_w_hh, dec_b_ih, dec_b_hh,
                                    out, dumpG);
}